// Round 9
// baseline (242.335 us; speedup 1.0000x reference)
//
#include <hip/hip_runtime.h>

// DynamicConv2d: B=16, CIN=COUT=64, K=3, H=W=192, OH=OW=190, DEG=64, HID=256
// out[b][co][oy][ox] = sum_{ci,ky,kx} w[b][co][ci][ky][kx] * x[b][ci][oy+ky][ox+kx]
// w = (relu(deg@W1+b1)@W2+b2).reshape(B,COUT,CIN,3,3)

typedef __bf16 bf16x8 __attribute__((ext_vector_type(8)));
typedef float  f32x4  __attribute__((ext_vector_type(4)));

#define NB   16
#define CIN  64
#define COUT 64
#define HW   192
#define OHW  190
#define NPIX (HW*HW)        // 36864
#define NW2  (COUT*CIN*9)   // 36864

__device__ __forceinline__ unsigned short f2bf(float f) {
    union { float f; unsigned int u; } v; v.f = f;
    unsigned int r = v.u + 0x7FFFu + ((v.u >> 16) & 1u);   // RNE
    return (unsigned short)(r >> 16);
}

// ---------------- k23: transpose (blocks 0..9215) + weight-gen (blocks 9216..10367) ----------------
__global__ __launch_bounds__(256)
void k23(const float* __restrict__ x, unsigned short* __restrict__ xT,
         const float* __restrict__ deg, const float* __restrict__ W1,
         const float* __restrict__ b1, const float* __restrict__ W2,
         const float* __restrict__ b2, unsigned short* __restrict__ Aw) {
    __shared__ __align__(16) char smem[37376];
    const int bid = blockIdx.x;
    const int t   = threadIdx.x;

    if (bid < 9216) {
        // ---- transpose: xT[b][p][ci] bf16 = x[b][ci][p] ----
        float (*tile)[65] = (float (*)[65])smem;   // 16640 B
        int b  = bid / 576;
        int p0 = (bid - b*576) * 64;
        const float* xb = x + (size_t)b * CIN * NPIX;
        {
            int c  = (t & 15) * 4;
            int r0 = t >> 4;
            #pragma unroll
            for (int i = 0; i < 4; ++i) {
                int ci = r0 + 16*i;
                float4 v = *(const float4*)(xb + (size_t)ci*NPIX + p0 + c);
                tile[ci][c] = v.x; tile[ci][c+1] = v.y; tile[ci][c+2] = v.z; tile[ci][c+3] = v.w;
            }
        }
        __syncthreads();
        {
            int ci8 = (t & 7) * 8;
            int pr0 = t >> 3;        // 0..31
            #pragma unroll
            for (int i = 0; i < 2; ++i) {
                int pl = pr0 + 32*i;
                union { uint4 v; unsigned short u[8]; } pk;
                #pragma unroll
                for (int j = 0; j < 8; ++j) pk.u[j] = f2bf(tile[ci8 + j][pl]);
                *(uint4*)(&xT[((size_t)b*NPIX + p0 + pl)*CIN + ci8]) = pk.v;
            }
        }
    } else {
        // ---- weight generator ----
        float* degs = (float*)smem;                 // 4096 B
        float* hs   = degs + 16*64;                 // 16384 B
        float (*red)[16][33] = (float (*)[16][33])(hs + 16*256);   // 16896 B
        int nb = bid - 9216;                        // 0..1151

        for (int i = t; i < 16*64; i += 256) degs[i] = deg[i];
        __syncthreads();
        {
            float acc[16];
            float bias = b1[t];
            #pragma unroll
            for (int bb2 = 0; bb2 < 16; ++bb2) acc[bb2] = bias;
            for (int d = 0; d < 64; ++d) {
                float w = W1[d*256 + t];
                #pragma unroll
                for (int bb2 = 0; bb2 < 16; ++bb2) acc[bb2] += degs[bb2*64 + d] * w;
            }
            #pragma unroll
            for (int bb2 = 0; bb2 < 16; ++bb2) hs[bb2*256 + t] = fmaxf(acc[bb2], 0.f);
        }
        __syncthreads();

        int nl = t & 31;
        int kc = t >> 5;
        int n  = nb * 32 + nl;
        float acc[16] = {};
        #pragma unroll
        for (int kk = 0; kk < 32; ++kk) {
            int k = kc*32 + kk;
            float w = W2[(size_t)k*NW2 + n];
            #pragma unroll
            for (int b = 0; b < 16; ++b) acc[b] += hs[b*256 + k] * w;
        }
        #pragma unroll
        for (int b = 0; b < 16; ++b) red[kc][b][nl] = acc[b];
        __syncthreads();

        for (int i = t; i < 512; i += 256) {
            int b  = i >> 5;
            int nn = i & 31;
            int n2 = nb * 32 + nn;
            float s = b2[n2];
            #pragma unroll
            for (int k = 0; k < 8; ++k) s += red[k][b][nn];
            int co  = n2 / 576;
            int rem = n2 - co*576;
            int ci  = rem / 9;
            int tap = rem - ci*9;
            Aw[(((b*9 + tap)*COUT + co)*CIN) + ci] = f2bf(s);
        }
    }
}

// ---------------- k4: MFMA conv, NO LDS, ky-reuse ----------------
// grid 2304 (16b x 24ty x 6tx), block 256 (4 waves = row-pairs), tile 64co x 8y x 32x.
// Zero barriers, zero LDS: B-frags are per-lane 16B loads from channels-last xT
// (px stride = 128 B so every tap shift stays 16B-aligned). Per (cc,kx) step a wave
// loads 8 B-frags (4 rows x 2 col-groups) and fires 48 MFMAs, rows shared across the
// 3 ky's -> requested B bytes 2.75x footprint (vs 9x in the R4 version that thrashed).
// A streamed with one-step-ahead prefetch. 12 desynced waves/CU give the TLP.
__global__ __launch_bounds__(256, 3)
void k4_conv(const unsigned short* __restrict__ xT, const unsigned short* __restrict__ Aw,
             float* __restrict__ out) {
    const int tid = threadIdx.x;

    // bijective XCD swizzle: 2304 % 8 == 0, 288 consecutive tiles per XCD
    int bid = blockIdx.x;
    int wg  = (bid & 7) * 288 + (bid >> 3);
    int b   = wg / 144;
    int ry  = wg - b*144;
    int ty  = ry / 6;
    int tx  = ry - ty*6;
    const int x0 = tx * 32;
    const int y0 = ty * 8;

    const int wv  = tid >> 6;    // wave 0..3 -> output rows 2wv, 2wv+1
    const int l   = tid & 63;
    const int l15 = l & 15;
    const int lg  = l >> 4;      // 0..3

    const unsigned short* xTb = xT + (size_t)b * NPIX * CIN;
    const unsigned short* Al  = Aw + b*(9*COUT*CIN) + l15*CIN + lg*8;

    // 4 input-row base pointers for this wave (rows 2wv .. 2wv+3, clamped)
    const unsigned short* rowp[4];
    #pragma unroll
    for (int q = 0; q < 4; ++q) {
        int gy = y0 + 2*wv + q; if (gy > 191) gy = 191;
        rowp[q] = xTb + (size_t)gy * HW * CIN;
    }

    f32x4 acc[4][4] = {};        // [m co-group][n = r*2+xb]

    // A double-buffer: 12 frags per (cc,kx) step = [ky*4+m]
    bf16x8 aA[12], aB[12];
    #pragma unroll
    for (int ky = 0; ky < 3; ++ky)
        #pragma unroll
        for (int m = 0; m < 4; ++m)
            aA[ky*4+m] = *(const bf16x8*)(Al + (ky*3 + 0)*4096 + m*1024 + 0*32);

    #pragma unroll
    for (int st = 0; st < 6; ++st) {
        const int cc = st / 3, kx = st - 3*(st/3);
        // prefetch A for next step
        if (st < 5) {
            const int ns = st + 1;
            const int ncc = ns / 3, nkx = ns - 3*(ns/3);
            if (st & 1) {
                #pragma unroll
                for (int ky = 0; ky < 3; ++ky)
                    #pragma unroll
                    for (int m = 0; m < 4; ++m)
                        aA[ky*4+m] = *(const bf16x8*)(Al + (ky*3 + nkx)*4096 + m*1024 + ncc*32);
            } else {
                #pragma unroll
                for (int ky = 0; ky < 3; ++ky)
                    #pragma unroll
                    for (int m = 0; m < 4; ++m)
                        aB[ky*4+m] = *(const bf16x8*)(Al + (ky*3 + nkx)*4096 + m*1024 + ncc*32);
            }
        }
        // B: 4 rows x 2 col-groups, loaded once per step, reused across 3 ky
        bf16x8 bb[4][2];
        #pragma unroll
        for (int q = 0; q < 4; ++q)
            #pragma unroll
            for (int xb = 0; xb < 2; ++xb) {
                int gx = x0 + xb*16 + l15 + kx; if (gx > 191) gx = 191;
                bb[q][xb] = *(const bf16x8*)(rowp[q] + (size_t)gx*CIN + cc*32 + lg*8);
            }
        #pragma unroll
        for (int ky = 0; ky < 3; ++ky)
            #pragma unroll
            for (int m = 0; m < 4; ++m)
                #pragma unroll
                for (int r = 0; r < 2; ++r)
                    #pragma unroll
                    for (int xb = 0; xb < 2; ++xb)
                        acc[m][r*2+xb] = __builtin_amdgcn_mfma_f32_16x16x32_bf16(
                            (st & 1) ? aB[ky*4+m] : aA[ky*4+m],
                            bb[ky+r][xb], acc[m][r*2+xb], 0, 0, 0);
    }

    // ---- epilogue: D col = lane&15 (ox), row = (lane>>4)*4+j (co) ----
    #pragma unroll
    for (int m = 0; m < 4; ++m)
        #pragma unroll
        for (int r = 0; r < 2; ++r)
            #pragma unroll
            for (int xb = 0; xb < 2; ++xb) {
                int oy = y0 + 2*wv + r;
                int ox = x0 + xb*16 + l15;
                if (oy < OHW && ox < OHW) {
                    f32x4 v = acc[m][r*2+xb];
                    #pragma unroll
                    for (int j = 0; j < 4; ++j) {
                        int co = m*16 + lg*4 + j;
                        out[((size_t)(b*COUT + co)*OHW + oy)*OHW + ox] = v[j];
                    }
                }
            }
}

extern "C" void kernel_launch(void* const* d_in, const int* in_sizes, int n_in,
                              void* d_out, int out_size, void* d_ws, size_t ws_size,
                              hipStream_t stream) {
    const float* x   = (const float*)d_in[0];
    const float* deg = (const float*)d_in[1];
    const float* W1  = (const float*)d_in[2];
    const float* b1  = (const float*)d_in[3];
    const float* W2  = (const float*)d_in[4];
    const float* b2  = (const float*)d_in[5];
    float* out = (float*)d_out;

    unsigned short* Aw = (unsigned short*)d_ws;                       // 1.18 MB
    unsigned short* xT = (unsigned short*)((char*)d_ws + (size_t)NB*9*COUT*CIN*2);

    k23<<<9216 + 1152, 256, 0, stream>>>(x, xT, deg, W1, b1, W2, b2, Aw);
    k4_conv<<<2304, 256, 0, stream>>>(xT, Aw, out);
}